// Round 6
// baseline (27.338 us; speedup 1.0000x reference)
//
#include <hip/hip_runtime.h>

// 3x3 median filter, REFLECT padding, NHWC (8,512,512,8) f32.
// Separable identity: row-triples reduced to (lo,mi,hi) = (min3,med3,max3);
// median9 = med3(max3(lo_r..), med3(mid_r..), min3(hi_r..)).
// Each thread: vertical strip of RS=16 outputs for one float4 (4 channels),
// rolling 3-row window of reduced triples (low VGPR, pipelined loads).
// R5 A/B: plain stores (isolating the nontemporal-store variable from R2).

__device__ __forceinline__ float4 f4min3(float4 a, float4 b, float4 c) {
  float4 r;
  r.x = fminf(fminf(a.x, b.x), c.x);
  r.y = fminf(fminf(a.y, b.y), c.y);
  r.z = fminf(fminf(a.z, b.z), c.z);
  r.w = fminf(fminf(a.w, b.w), c.w);
  return r;
}
__device__ __forceinline__ float4 f4max3(float4 a, float4 b, float4 c) {
  float4 r;
  r.x = fmaxf(fmaxf(a.x, b.x), c.x);
  r.y = fmaxf(fmaxf(a.y, b.y), c.y);
  r.z = fmaxf(fmaxf(a.z, b.z), c.z);
  r.w = fmaxf(fmaxf(a.w, b.w), c.w);
  return r;
}
__device__ __forceinline__ float4 f4med3(float4 a, float4 b, float4 c) {
  float4 r;
  r.x = __builtin_amdgcn_fmed3f(a.x, b.x, c.x);
  r.y = __builtin_amdgcn_fmed3f(a.y, b.y, c.y);
  r.z = __builtin_amdgcn_fmed3f(a.z, b.z, c.z);
  r.w = __builtin_amdgcn_fmed3f(a.w, b.w, c.w);
  return r;
}

__global__ __launch_bounds__(256) void MedianFilter2D_kernel(
    const float* __restrict__ x, float* __restrict__ y) {
  constexpr int H = 512, W = 512, C4 = 2;  // C=8 floats -> 2 float4/pixel
  constexpr int RS = 16;                   // output rows per thread

  const int idx = blockIdx.x * 256 + threadIdx.x;
  const int c4 = idx & 1;
  const int w  = (idx >> 1) & (W - 1);
  const int hq = (idx >> 10) & (H / RS - 1);  // wave-uniform
  const int b  = idx >> 15;                   // wave-uniform

  const int h0 = hq * RS;

  // reflect (mirror, edge not repeated)
  const int wm = (w == 0) ? 1 : w - 1;
  const int wp = (w == W - 1) ? W - 2 : w + 1;

  const float4* __restrict__ xv = reinterpret_cast<const float4*>(x);
  float4* __restrict__ yv = reinterpret_cast<float4*>(y);

  const int bbase = b * (H * W * C4);
  const int colm = wm * C4 + c4, col0 = w * C4 + c4, colp = wp * C4 + c4;

  // Rolling 3-slot window of row triple-reductions.
  float4 lo[3], mi[3], hi[3];

  // preload rows h0-1 (reflected) and h0 into slots 0,1
  {
    const int rtop = (h0 == 0) ? 1 : h0 - 1;  // wave-uniform reflect
    const int rb = bbase + rtop * (W * C4);
    const float4 a = xv[rb + colm];
    const float4 bb = xv[rb + col0];
    const float4 c = xv[rb + colp];
    lo[0] = f4min3(a, bb, c);
    mi[0] = f4med3(a, bb, c);
    hi[0] = f4max3(a, bb, c);
  }
  {
    const int rb = bbase + h0 * (W * C4);
    const float4 a = xv[rb + colm];
    const float4 bb = xv[rb + col0];
    const float4 c = xv[rb + colp];
    lo[1] = f4min3(a, bb, c);
    mi[1] = f4med3(a, bb, c);
    hi[1] = f4max3(a, bb, c);
  }

  const int obase = bbase + h0 * (W * C4) + col0;
#pragma unroll
  for (int r = 0; r < RS; ++r) {
    // load row h0+r+1 (reflect at bottom), reduce into slot (r+2)%3
    {
      int rr = h0 + r + 1;
      rr = (rr > H - 1) ? H - 2 : rr;  // wave-uniform
      const int rb = bbase + rr * (W * C4);
      const float4 a = xv[rb + colm];
      const float4 bb = xv[rb + col0];
      const float4 c = xv[rb + colp];
      const int s = (r + 2) % 3;
      lo[s] = f4min3(a, bb, c);
      mi[s] = f4med3(a, bb, c);
      hi[s] = f4max3(a, bb, c);
    }
    const int s0 = r % 3, s1 = (r + 1) % 3, s2 = (r + 2) % 3;
    const float4 lmax = f4max3(lo[s0], lo[s1], lo[s2]);
    const float4 mmed = f4med3(mi[s0], mi[s1], mi[s2]);
    const float4 hmin = f4min3(hi[s0], hi[s1], hi[s2]);
    yv[obase + r * (W * C4)] = f4med3(lmax, mmed, hmin);
  }
}

extern "C" void kernel_launch(void* const* d_in, const int* in_sizes, int n_in,
                              void* d_out, int out_size, void* d_ws, size_t ws_size,
                              hipStream_t stream) {
  const float* x = (const float*)d_in[0];
  float* y = (float*)d_out;
  // threads: 8 * (512/16) * 512 * 2 = 262,144 -> 1024 blocks of 256
  const int threads_total = 8 * (512 / 16) * 512 * 2;
  MedianFilter2D_kernel<<<threads_total / 256, 256, 0, stream>>>(x, y);
}